// Round 3
// baseline (159.414 us; speedup 1.0000x reference)
//
#include <hip/hip_runtime.h>
#include <math.h>

// SineSPE on MI355X. B=2 L=1024 H=8 D=64 S=10 R=128.
// qhat/khat = 32 GEMMs [1024 x 1280]x[1280 x 128], A built on the fly from trig.
// K reordered as [dh(2)][s(10)][dl(32)] pairs so per-tile s is constant and d is
// a static lane offset -> no LDS, no barriers, no dynamic register indexing.

typedef short bf16x8 __attribute__((ext_vector_type(8)));
typedef float f32x16 __attribute__((ext_vector_type(16)));

__device__ __forceinline__ unsigned int rnd_bf16(float x) {
    union { float f; unsigned int u; } v; v.f = x;
    return v.u + 0x8000u;
}
// pack: cos -> low u16 (even k), sin -> high u16 (odd k)
__device__ __forceinline__ unsigned int pack_bf16(float c, float s) {
    return __builtin_amdgcn_perm(rnd_bf16(s), rnd_bf16(c), 0x07060302u);
}

// zt per (bh, kb), kb = dh*10 + s. Tile = 16KB: [g(4)][r(128)][c(16)] shorts,
// col kkl = g*16 + c = 2*dl + cs (dl = d - dh*32; cs 0=cos,1=sin).
// frof[qk][h][s][d] = {sigmoid(freq)/2 (rev/step), qk==0 ? off/2pi : 0}
__global__ __launch_bounds__(256) void prep_z(
    const float* __restrict__ freqs, const float* __restrict__ offsets,
    const float* __restrict__ gains, const float* __restrict__ z,
    unsigned short* __restrict__ zt, float2* __restrict__ frof)
{
    const float scale = 0.011048543456039806f;  // 1/sqrt(R*D)
    int bid = blockIdx.x;            // 0..319
    int bh = bid / 20, kb = bid % 20;
    int h = bh & 7;
    int dh = kb / 10, s = kb % 10;
    int t = threadIdx.x;
    __shared__ unsigned short tr[128 * 65];

    if (t < 16) {                    // param tables: i indexes [h][s][d]
        int i = bid * 16 + t;        // 0..5119
        int hh = i / 640; int rem = i - hh * 640;
        int ss = rem >> 6, dd = rem & 63;
        int src = (hh * 64 + dd) * 10 + ss;
        float fr = 0.5f / (1.0f + __expf(-freqs[src]));
        frof[i] = make_float2(fr, offsets[src] * 0.15915494309189535f);
        frof[5120 + i] = make_float2(fr, 0.0f);
    }

    for (int i = 0; i < 32; i++) {
        int e = i * 256 + t;         // kkl = e>>7, r = e&127 (coalesced on r)
        int kkl = e >> 7, r = e & 127;
        int d = dh * 32 + (kkl >> 1);
        int tt = 2 * s + (kkl & 1);              // index into z's 2S dim
        int jm = (tt < 10) ? tt : tt - 10;       // concat([g,g]) gain layout
        float gn = gains[(h * 64 + d) * 10 + jm];
        float g = fmaxf(gn, 0.0f) + log1pf(__expf(-fabsf(gn)));  // softplus
        float val = z[((size_t)(bh * 64 + d) * 20 + tt) * 128 + r] * g * scale;
        tr[r * 65 + kkl] = (unsigned short)(rnd_bf16(val) >> 16);
    }
    __syncthreads();
    size_t ob = (size_t)bid * 8192;
    for (int i = 0; i < 32; i++) {
        int e2 = i * 256 + t;
        int r = e2 >> 6, kkl = e2 & 63;
        zt[ob + (size_t)((kkl >> 4) * 2048 + r * 16 + (kkl & 15))] = tr[r * 65 + kkl];
    }
}

// grid 512, block 256 (4 waves). Wave = (qk, b, h, ks, ltile): 64 rows x 128 N,
// K-split 4 (320 k each). No LDS, no barriers; split-K reduced via atomicAdd.
__global__ __launch_bounds__(256, 2) void spe_gemm(
    const float* __restrict__ queries, const float* __restrict__ keys,
    const float2* __restrict__ frof, const unsigned short* __restrict__ zt,
    float* __restrict__ out)
{
    int bid = blockIdx.x;
    int h = bid & 7;                 // XCD swizzle: same-h blocks share an XCD
    int i = bid >> 3;                // 0..63
    int qk = i & 1;
    int b = (i >> 1) & 1;
    int ks = (i >> 2) & 3;
    int ltg = i >> 4;                // 0..3
    int dh = ks >> 1;                // which d-half
    int sb = (ks & 1) * 5;           // s range base

    int t = threadIdx.x;
    int w = t >> 6;
    int lane = t & 63;
    int ml = lane & 31, hi = lane >> 5;
    int l0 = (ltg * 4 + w) * 64;

    const float* qsrc = qk ? keys : queries;
    const float2* fo_base = frof + qk * 5120 + h * 640 + dh * 32 + hi * 4;
    const unsigned short* ztbh = zt + (size_t)((b * 8 + h) * 20) * 8192;

    // ---- prologue: q fragments (f32, all-static indexing afterwards) ----
    float4 qf[2][4];
    float lf[2];
    #pragma unroll
    for (int mf = 0; mf < 2; mf++) {
        int row = l0 + mf * 32 + ml;
        lf[mf] = (float)row;
        const float* rp = qsrc + ((size_t)(b * 1024 + row) * 8 + h) * 64 + dh * 32 + hi * 4;
        #pragma unroll
        for (int g = 0; g < 4; g++)
            qf[mf][g] = *(const float4*)(rp + g * 8);
    }

    f32x16 acc[2][4] = {};

    for (int it = 0; it < 5; it++) {
        int kb = dh * 10 + sb + it;
        const unsigned short* tile = ztbh + (size_t)kb * 8192;
        const float2* fop = fo_base + (size_t)(sb + it) * 64;

        // ---- A fragments: d = dh*32 + g*8 + hi*4 + j (static per slot) ----
        unsigned int af[2][4][4];
        #pragma unroll
        for (int g = 0; g < 4; g++) {
            const float4* f4 = (const float4*)(fop + g * 8);
            float4 fA = f4[0], fB = f4[1];   // pairs j0,j1 | j2,j3 = {fr,off}
            #pragma unroll
            for (int mf = 0; mf < 2; mf++) {
                float L = lf[mf];
                float4 q4 = qf[mf][g];
                float p0 = __builtin_amdgcn_fractf(fmaf(fA.x, L, fA.y));
                float p1 = __builtin_amdgcn_fractf(fmaf(fA.z, L, fA.w));
                float p2 = __builtin_amdgcn_fractf(fmaf(fB.x, L, fB.y));
                float p3 = __builtin_amdgcn_fractf(fmaf(fB.z, L, fB.w));
                af[mf][g][0] = pack_bf16(__builtin_amdgcn_cosf(p0) * q4.x,
                                         __builtin_amdgcn_sinf(p0) * q4.x);
                af[mf][g][1] = pack_bf16(__builtin_amdgcn_cosf(p1) * q4.y,
                                         __builtin_amdgcn_sinf(p1) * q4.y);
                af[mf][g][2] = pack_bf16(__builtin_amdgcn_cosf(p2) * q4.z,
                                         __builtin_amdgcn_sinf(p2) * q4.z);
                af[mf][g][3] = pack_bf16(__builtin_amdgcn_cosf(p3) * q4.w,
                                         __builtin_amdgcn_sinf(p3) * q4.w);
            }
        }

        // ---- MFMA: B straight from L1/L2, coalesced 16B/lane; feeds 2 MFMAs ----
        #pragma unroll
        for (int g = 0; g < 4; g++) {
            #pragma unroll
            for (int nt = 0; nt < 4; nt++) {
                bf16x8 bb = *(const bf16x8*)(tile + g * 2048 + (nt * 32 + ml) * 16 + hi * 8);
                acc[0][nt] = __builtin_amdgcn_mfma_f32_32x32x16_bf16(
                    *(const bf16x8*)&af[0][g][0], bb, acc[0][nt], 0, 0, 0);
                acc[1][nt] = __builtin_amdgcn_mfma_f32_32x32x16_bf16(
                    *(const bf16x8*)&af[1][g][0], bb, acc[1][nt], 0, 0, 0);
            }
        }
    }

    // ---- epilogue: split-K reduce via f32 atomics (out pre-zeroed) ----
    // C/D layout: col = lane&31, row = (reg&3) + 8*(reg>>2) + 4*hi
    float* ob = out + (size_t)qk * 2097152 + (size_t)b * 1048576 + h * 128;
    #pragma unroll
    for (int mf = 0; mf < 2; mf++) {
        #pragma unroll
        for (int nt = 0; nt < 4; nt++) {
            int col = nt * 32 + ml;
            #pragma unroll
            for (int reg = 0; reg < 16; reg++) {
                int row = l0 + mf * 32 + (reg & 3) + 8 * (reg >> 2) + 4 * hi;
                atomicAdd(ob + (size_t)row * 1024 + col, acc[mf][nt][reg]);
            }
        }
    }
}

extern "C" void kernel_launch(void* const* d_in, const int* in_sizes, int n_in,
                              void* d_out, int out_size, void* d_ws, size_t ws_size,
                              hipStream_t stream) {
    const float* queries = (const float*)d_in[0];
    const float* keys    = (const float*)d_in[1];
    const float* freqs   = (const float*)d_in[2];
    const float* offsets = (const float*)d_in[3];
    const float* gains   = (const float*)d_in[4];
    const float* z       = (const float*)d_in[5];
    float* out = (float*)d_out;

    float2* frof = (float2*)d_ws;                               // 2*5120 float2 (80KB)
    unsigned short* zt = (unsigned short*)((char*)d_ws + 2 * 5120 * sizeof(float2));

    prep_z<<<320, 256, 0, stream>>>(freqs, offsets, gains, z, zt, frof);
    hipMemsetAsync(d_out, 0, (size_t)out_size * sizeof(float), stream);
    spe_gemm<<<512, 256, 0, stream>>>(queries, keys, frof, zt, out);
}

// Round 4
// 104.136 us; speedup vs baseline: 1.5308x; 1.5308x over previous
//
#include <hip/hip_runtime.h>
#include <math.h>

// SineSPE MI355X. B=2 L=1024 H=8 D=64 S=10 R=128.
// 32 GEMMs [1024 x 1280]x[1280 x 128]; A(omega*q) built on the fly in LDS.
// K order: [dh(2)][s(10)][dl(32)] pairs -> per 64-k tile s is constant, d affine.
// No atomics, no split-K. 1024 blocks -> 4 blocks/CU, 16 waves/CU.

typedef short bf16x8 __attribute__((ext_vector_type(8)));
typedef float f32x16 __attribute__((ext_vector_type(16)));

__device__ __forceinline__ unsigned int rnd_bf16(float x) {
    union { float f; unsigned int u; } v; v.f = x;
    return v.u + 0x8000u;
}
// low short = bf16(c) (even k = cos), high short = bf16(s) (odd k = sin)
__device__ __forceinline__ unsigned int pack_bf16(float c, float s) {
    return __builtin_amdgcn_perm(rnd_bf16(s), rnd_bf16(c), 0x07060302u);
}

// gs[(h*64+d)*20 + tt] = softplus(gains[h,d,tt%10]) / sqrt(R*D)
// frof[qk*5120 + h*640 + s*64 + d] = {sigmoid(freq)/2, qk==0 ? off/2pi : 0}
__global__ __launch_bounds__(256) void prep_tab(
    const float* __restrict__ freqs, const float* __restrict__ offsets,
    const float* __restrict__ gains, float2* __restrict__ frof,
    float* __restrict__ gs)
{
    int i = blockIdx.x * 256 + threadIdx.x;        // 0..10239
    int hd = i / 20, tt = i - hd * 20;
    int jm = (tt < 10) ? tt : tt - 10;
    float gn = gains[hd * 10 + jm];
    float g = fmaxf(gn, 0.0f) + log1pf(__expf(-fabsf(gn)));
    gs[i] = g * 0.011048543456039806f;
    if (i < 5120) {
        int hh = i / 640, rem = i - hh * 640;
        int ss = rem >> 6, dd = rem & 63;
        int src = (hh * 64 + dd) * 10 + ss;
        float fr = 0.5f / (1.0f + __expf(-freqs[src]));
        frof[i] = make_float2(fr, offsets[src] * 0.15915494309189535f);
        frof[5120 + i] = make_float2(fr, 0.0f);
    }
}

// zt tile per (bh, kb=dh*10+s): 16KB = [g(4)][r(128)][c(16)] shorts,
// kkl = g*16+c = 2*dl + cs. LDS-free: coalesced dword reads, uint4 writes.
__global__ __launch_bounds__(256) void prep_z(
    const float* __restrict__ z, const float* __restrict__ gs,
    uint4* __restrict__ zt)
{
    int bid = blockIdx.x;               // bh*20 + kb
    int bh = bid / 20, kb = bid - bh * 20;
    int h = bh & 7;
    int dh = (kb >= 10) ? 1 : 0, s = kb - dh * 10;
    int t = threadIdx.x;
    const float* zb = z + (size_t)bh * 163840;     // [d][tt][r]
    const float* gsb = gs + h * 1280;              // [d][tt]
    uint4* outb = zt + (size_t)bid * 1024;

    #pragma unroll
    for (int i = 0; i < 4; i++) {
        int e = i * 256 + t;
        int r = (e >> 1) & 127, c8 = e & 1;
        int dl0 = i * 8 + c8 * 4;                  // pair (dl) base for this u4
        unsigned int u[4];
        #pragma unroll
        for (int m = 0; m < 4; m++) {
            int d = dh * 32 + dl0 + m;
            float ve = zb[((size_t)d * 20 + 2 * s) * 128 + r] * gsb[d * 20 + 2 * s];
            float vo = zb[((size_t)d * 20 + 2 * s + 1) * 128 + r] * gsb[d * 20 + 2 * s + 1];
            u[m] = pack_bf16(ve, vo);
        }
        outb[e] = make_uint4(u[0], u[1], u[2], u[3]);
    }
}

__global__ __launch_bounds__(256, 4) void spe_gemm(
    const float* __restrict__ queries, const float* __restrict__ keys,
    const float2* __restrict__ frof, const unsigned short* __restrict__ zt,
    float* __restrict__ out)
{
    __shared__ unsigned int At[2][1024];   // [buf][row*32 + swz-chunk*4 + j], 8KB

    int bid = blockIdx.x;
    int h = bid & 7;                       // XCD swizzle: same-h -> same XCD
    int u = bid >> 3;
    int qk = u & 1, b = (u >> 1) & 1, lt = u >> 2;   // lt 0..31
    int l0 = lt * 32;

    int t = threadIdx.x, w = t >> 6, lane = t & 63;
    int ml = lane & 31, hi = lane >> 5;
    int arow = t >> 3, pg = t & 7;         // A-build: row 0..31, pair-group 0..7

    const float* qsrc = (qk ? keys : queries)
                      + ((size_t)(b * 1024 + l0 + arow) * 8 + h) * 64 + pg * 4;
    const float2* fob = frof + qk * 5120 + h * 640 + pg * 4;
    const unsigned short* bbase = zt + (size_t)(b * 8 + h) * 163840
                                + (w * 32 + ml) * 16 + hi * 8;
    float lf = (float)(l0 + arow);
    unsigned int awz = arow * 32 + ((pg ^ (arow & 7)) << 2);  // A-write dword idx

    float4 qf = *(const float4*)(qsrc);    // dh=0 q slice

    // ---- build tile 0 (dh=0, s=0) into buf0 ----
    {
        const float4* fp = (const float4*)(fob);
        float4 fA = fp[0], fB = fp[1];
        float p0 = __builtin_amdgcn_fractf(fmaf(fA.x, lf, fA.y));
        float p1 = __builtin_amdgcn_fractf(fmaf(fA.z, lf, fA.w));
        float p2 = __builtin_amdgcn_fractf(fmaf(fB.x, lf, fB.y));
        float p3 = __builtin_amdgcn_fractf(fmaf(fB.z, lf, fB.w));
        uint4 a4;
        a4.x = pack_bf16(__builtin_amdgcn_cosf(p0) * qf.x, __builtin_amdgcn_sinf(p0) * qf.x);
        a4.y = pack_bf16(__builtin_amdgcn_cosf(p1) * qf.y, __builtin_amdgcn_sinf(p1) * qf.y);
        a4.z = pack_bf16(__builtin_amdgcn_cosf(p2) * qf.z, __builtin_amdgcn_sinf(p2) * qf.z);
        a4.w = pack_bf16(__builtin_amdgcn_cosf(p3) * qf.w, __builtin_amdgcn_sinf(p3) * qf.w);
        *(uint4*)&At[0][awz] = a4;
    }

    f32x16 acc = {};

    #pragma unroll 2
    for (int kb = 0; kb < 20; kb++) {
        __syncthreads();                   // tile kb writes visible; old reads done
        int cur = kb & 1;

        // B loads for tile kb first: latency hides under trig below
        const unsigned short* tp = bbase + (size_t)kb * 8192;
        bf16x8 b0 = *(const bf16x8*)(tp);
        bf16x8 b1 = *(const bf16x8*)(tp + 2048);
        bf16x8 b2 = *(const bf16x8*)(tp + 4096);
        bf16x8 b3 = *(const bf16x8*)(tp + 6144);

        // build tile kb+1 into the other buffer
        if (kb < 19) {
            int kn = kb + 1;
            int dh = (kn >= 10) ? 1 : 0;
            int s = kn - dh * 10;
            if (kn == 10) qf = *(const float4*)(qsrc + 32);   // dh=1 q slice
            const float4* fp = (const float4*)(fob + s * 64 + dh * 32);
            float4 fA = fp[0], fB = fp[1];
            float p0 = __builtin_amdgcn_fractf(fmaf(fA.x, lf, fA.y));
            float p1 = __builtin_amdgcn_fractf(fmaf(fA.z, lf, fA.w));
            float p2 = __builtin_amdgcn_fractf(fmaf(fB.x, lf, fB.y));
            float p3 = __builtin_amdgcn_fractf(fmaf(fB.z, lf, fB.w));
            uint4 a4;
            a4.x = pack_bf16(__builtin_amdgcn_cosf(p0) * qf.x, __builtin_amdgcn_sinf(p0) * qf.x);
            a4.y = pack_bf16(__builtin_amdgcn_cosf(p1) * qf.y, __builtin_amdgcn_sinf(p1) * qf.y);
            a4.z = pack_bf16(__builtin_amdgcn_cosf(p2) * qf.z, __builtin_amdgcn_sinf(p2) * qf.z);
            a4.w = pack_bf16(__builtin_amdgcn_cosf(p3) * qf.w, __builtin_amdgcn_sinf(p3) * qf.w);
            *(uint4*)&At[cur ^ 1][awz] = a4;
        }

        // MFMA over 4 k-steps; A-frag from swizzled LDS (conflict-free b128)
        #pragma unroll
        for (int ks = 0; ks < 4; ks++) {
            bf16x8 a = *(const bf16x8*)&At[cur][ml * 32 + (((ks * 2 + hi) ^ (ml & 7)) << 2)];
            bf16x8 bb = (ks == 0) ? b0 : (ks == 1) ? b1 : (ks == 2) ? b2 : b3;
            acc = __builtin_amdgcn_mfma_f32_32x32x16_bf16(a, bb, acc, 0, 0, 0);
        }
    }

    // ---- epilogue: each element stored once. C/D: col=lane&31, row=(reg&3)+8*(reg>>2)+4*hi
    float* ob = out + (size_t)qk * 2097152 + (size_t)b * 1048576
              + (size_t)h * 128 + w * 32 + ml;
    #pragma unroll
    for (int reg = 0; reg < 16; reg++) {
        int row = l0 + (reg & 3) + 8 * (reg >> 2) + 4 * hi;
        ob[(size_t)row * 1024] = acc[reg];
    }
}

extern "C" void kernel_launch(void* const* d_in, const int* in_sizes, int n_in,
                              void* d_out, int out_size, void* d_ws, size_t ws_size,
                              hipStream_t stream) {
    const float* queries = (const float*)d_in[0];
    const float* keys    = (const float*)d_in[1];
    const float* freqs   = (const float*)d_in[2];
    const float* offsets = (const float*)d_in[3];
    const float* gains   = (const float*)d_in[4];
    const float* z       = (const float*)d_in[5];
    float* out = (float*)d_out;

    float2* frof = (float2*)d_ws;                          // 10240 float2 = 80KB
    float* gs = (float*)((char*)d_ws + 81920);             // 10240 f32 = 40KB
    uint4* zt = (uint4*)((char*)d_ws + 122880);            // 5.24MB bf16 tiles

    prep_tab<<<40, 256, 0, stream>>>(freqs, offsets, gains, frof, gs);
    prep_z<<<320, 256, 0, stream>>>(z, gs, zt);
    spe_gemm<<<1024, 256, 0, stream>>>(queries, keys, frof,
                                       (const unsigned short*)zt, out);
}

// Round 5
// 100.950 us; speedup vs baseline: 1.5791x; 1.0316x over previous
//
#include <hip/hip_runtime.h>
#include <math.h>

// SineSPE MI355X. B=2 L=1024 H=8 D=64 S=10 R=128.
// 32 GEMMs [1024 x 1280]x[1280 x 128]; A(omega*q) built on the fly in LDS.
// K order: [dh(2)][s(10)][dl(32)] pairs -> per 64-k tile s is constant, d affine.
// 2 dispatches: prep_z (z->bf16 tiles + param tables), spe_gemm (no atomics,
// 1024 blocks = 4 blocks/CU = 16 waves/CU, B-tile register prefetch).

typedef short bf16x8 __attribute__((ext_vector_type(8)));
typedef float f32x16 __attribute__((ext_vector_type(16)));

__device__ __forceinline__ unsigned int rnd_bf16(float x) {
    union { float f; unsigned int u; } v; v.f = x;
    return v.u + 0x8000u;
}
// low short = bf16(c) (even k = cos), high short = bf16(s) (odd k = sin)
__device__ __forceinline__ unsigned int pack_bf16(float c, float s) {
    return __builtin_amdgcn_perm(rnd_bf16(s), rnd_bf16(c), 0x07060302u);
}

// zt tile per (bh, kb=dh*10+s): 16KB = [g(4)][r(128)][c(16)] shorts, kkl=g*16+c=2*dl+cs.
// Also: frof[qk*5120 + h*640 + s*64 + d] = {sigmoid(freq)/2, qk==0 ? off/2pi : 0}
__global__ __launch_bounds__(256) void prep_z(
    const float* __restrict__ freqs, const float* __restrict__ offsets,
    const float* __restrict__ gains, const float* __restrict__ z,
    uint4* __restrict__ zt, float2* __restrict__ frof)
{
    const float scale = 0.011048543456039806f;     // 1/sqrt(R*D)
    int bid = blockIdx.x;                          // bh*20 + kb
    int bh = bid / 20, kb = bid - bh * 20;
    int h = bh & 7;
    int dh = (kb >= 10) ? 1 : 0, s = kb - dh * 10;
    int t = threadIdx.x;

    __shared__ float gsl[64];                      // [dl(32)][parity(2)]

    if (t < 16) {                                  // param tables (5120 total)
        int i = bid * 16 + t;
        int hh = i / 640, rem = i - hh * 640;
        int ss = rem >> 6, dd = rem & 63;
        int src = (hh * 64 + dd) * 10 + ss;
        float fr = 0.5f / (1.0f + __expf(-freqs[src]));
        frof[i] = make_float2(fr, offsets[src] * 0.15915494309189535f);
        frof[5120 + i] = make_float2(fr, 0.0f);
    }
    if (t < 64) {                                  // softplus-gain for this tile
        int dl = t >> 1, par = t & 1;
        int tt = 2 * s + par;
        int jm = (tt < 10) ? tt : tt - 10;
        float gn = gains[(h * 64 + dh * 32 + dl) * 10 + jm];
        gsl[t] = (fmaxf(gn, 0.0f) + log1pf(__expf(-fabsf(gn)))) * scale;
    }
    __syncthreads();

    const float* zb = z + (size_t)bh * 163840;     // [d][tt][r]
    uint4* outb = zt + (size_t)bid * 1024;

    #pragma unroll
    for (int i = 0; i < 4; i++) {
        int e = i * 256 + t;
        int r = (e >> 1) & 127, c8 = e & 1;
        int dl0 = i * 8 + c8 * 4;                  // dl base for this uint4
        unsigned int u[4];
        #pragma unroll
        for (int m = 0; m < 4; m++) {
            int dl = dl0 + m;
            int d = dh * 32 + dl;
            float ve = zb[((size_t)d * 20 + 2 * s) * 128 + r] * gsl[dl * 2];
            float vo = zb[((size_t)d * 20 + 2 * s + 1) * 128 + r] * gsl[dl * 2 + 1];
            u[m] = pack_bf16(ve, vo);
        }
        outb[e] = make_uint4(u[0], u[1], u[2], u[3]);
    }
}

__global__ __launch_bounds__(256, 4) void spe_gemm(
    const float* __restrict__ queries, const float* __restrict__ keys,
    const float2* __restrict__ frof, const unsigned short* __restrict__ zt,
    float* __restrict__ out)
{
    __shared__ unsigned int At[2][1024];   // [buf][row*32 + swz-chunk*4 + j], 8KB

    int bid = blockIdx.x;
    int h = bid & 7;                       // XCD swizzle: same-h -> same XCD
    int u = bid >> 3;
    int qk = u & 1, b = (u >> 1) & 1, lt = u >> 2;   // lt 0..31
    int l0 = lt * 32;

    int t = threadIdx.x, w = t >> 6, lane = t & 63;
    int ml = lane & 31, hi = lane >> 5;
    int arow = t >> 3, pg = t & 7;         // A-build: row 0..31, pair-group 0..7

    const float* qsrc = (qk ? keys : queries)
                      + ((size_t)(b * 1024 + l0 + arow) * 8 + h) * 64 + pg * 4;
    const float2* fob = frof + qk * 5120 + h * 640 + pg * 4;
    const unsigned short* bbase = zt + (size_t)(b * 8 + h) * 163840
                                + (w * 32 + ml) * 16 + hi * 8;
    float lf = (float)(l0 + arow);
    unsigned int awz = arow * 32 + ((pg ^ (arow & 7)) << 2);  // A-write dword idx

    float4 qf = *(const float4*)(qsrc);    // dh=0 q slice

    // ---- prologue: B tile 0 into regs; A tile 0 into buf0 ----
    bf16x8 n0 = *(const bf16x8*)(bbase);
    bf16x8 n1 = *(const bf16x8*)(bbase + 2048);
    bf16x8 n2 = *(const bf16x8*)(bbase + 4096);
    bf16x8 n3 = *(const bf16x8*)(bbase + 6144);
    {
        const float4* fp = (const float4*)(fob);
        float4 fA = fp[0], fB = fp[1];
        float p0 = __builtin_amdgcn_fractf(fmaf(fA.x, lf, fA.y));
        float p1 = __builtin_amdgcn_fractf(fmaf(fA.z, lf, fA.w));
        float p2 = __builtin_amdgcn_fractf(fmaf(fB.x, lf, fB.y));
        float p3 = __builtin_amdgcn_fractf(fmaf(fB.z, lf, fB.w));
        uint4 a4;
        a4.x = pack_bf16(__builtin_amdgcn_cosf(p0) * qf.x, __builtin_amdgcn_sinf(p0) * qf.x);
        a4.y = pack_bf16(__builtin_amdgcn_cosf(p1) * qf.y, __builtin_amdgcn_sinf(p1) * qf.y);
        a4.z = pack_bf16(__builtin_amdgcn_cosf(p2) * qf.z, __builtin_amdgcn_sinf(p2) * qf.z);
        a4.w = pack_bf16(__builtin_amdgcn_cosf(p3) * qf.w, __builtin_amdgcn_sinf(p3) * qf.w);
        *(uint4*)&At[0][awz] = a4;
    }

    f32x16 acc = {};

    #pragma unroll 2
    for (int kb = 0; kb < 20; kb++) {
        __syncthreads();                   // tile kb A-writes visible; old reads done
        int cur = kb & 1;

        // current B tile from prefetch regs
        bf16x8 c0 = n0, c1 = n1, c2 = n2, c3 = n3;

        // issue next B tile loads (in flight under this iter's MFMA block)
        int kn = (kb < 19) ? kb + 1 : 19;  // branchless clamp (kb=19 dup, unused)
        const unsigned short* tp = bbase + (size_t)kn * 8192;
        n0 = *(const bf16x8*)(tp);
        n1 = *(const bf16x8*)(tp + 2048);
        n2 = *(const bf16x8*)(tp + 4096);
        n3 = *(const bf16x8*)(tp + 6144);

        // build A tile kn into the other buffer (kb=19: writes never read)
        {
            int dh = (kn >= 10) ? 1 : 0;
            int s = kn - dh * 10;
            if (kn == 10) qf = *(const float4*)(qsrc + 32);   // dh=1 q slice
            const float4* fp = (const float4*)(fob + s * 64 + dh * 32);
            float4 fA = fp[0], fB = fp[1];
            float p0 = __builtin_amdgcn_fractf(fmaf(fA.x, lf, fA.y));
            float p1 = __builtin_amdgcn_fractf(fmaf(fA.z, lf, fA.w));
            float p2 = __builtin_amdgcn_fractf(fmaf(fB.x, lf, fB.y));
            float p3 = __builtin_amdgcn_fractf(fmaf(fB.z, lf, fB.w));
            uint4 a4;
            a4.x = pack_bf16(__builtin_amdgcn_cosf(p0) * qf.x, __builtin_amdgcn_sinf(p0) * qf.x);
            a4.y = pack_bf16(__builtin_amdgcn_cosf(p1) * qf.y, __builtin_amdgcn_sinf(p1) * qf.y);
            a4.z = pack_bf16(__builtin_amdgcn_cosf(p2) * qf.z, __builtin_amdgcn_sinf(p2) * qf.z);
            a4.w = pack_bf16(__builtin_amdgcn_cosf(p3) * qf.w, __builtin_amdgcn_sinf(p3) * qf.w);
            *(uint4*)&At[cur ^ 1][awz] = a4;
        }

        // MFMA over 4 k-steps; A-frag from swizzled LDS (conflict-free b128)
        #pragma unroll
        for (int ks = 0; ks < 4; ks++) {
            bf16x8 a = *(const bf16x8*)&At[cur][ml * 32 + (((ks * 2 + hi) ^ (ml & 7)) << 2)];
            bf16x8 bb = (ks == 0) ? c0 : (ks == 1) ? c1 : (ks == 2) ? c2 : c3;
            acc = __builtin_amdgcn_mfma_f32_32x32x16_bf16(a, bb, acc, 0, 0, 0);
        }
    }

    // ---- epilogue: each element stored once. C/D: col=lane&31, row=(reg&3)+8*(reg>>2)+4*hi
    float* ob = out + (size_t)qk * 2097152 + (size_t)b * 1048576
              + (size_t)h * 128 + w * 32 + ml;
    #pragma unroll
    for (int reg = 0; reg < 16; reg++) {
        int row = l0 + (reg & 3) + 8 * (reg >> 2) + 4 * hi;
        ob[(size_t)row * 1024] = acc[reg];
    }
}

extern "C" void kernel_launch(void* const* d_in, const int* in_sizes, int n_in,
                              void* d_out, int out_size, void* d_ws, size_t ws_size,
                              hipStream_t stream) {
    const float* queries = (const float*)d_in[0];
    const float* keys    = (const float*)d_in[1];
    const float* freqs   = (const float*)d_in[2];
    const float* offsets = (const float*)d_in[3];
    const float* gains   = (const float*)d_in[4];
    const float* z       = (const float*)d_in[5];
    float* out = (float*)d_out;

    float2* frof = (float2*)d_ws;                          // 10240 float2 = 80KB
    uint4* zt = (uint4*)((char*)d_ws + 81920);             // 5.24MB bf16 tiles

    prep_z<<<320, 256, 0, stream>>>(freqs, offsets, gains, z, zt, frof);
    spe_gemm<<<1024, 256, 0, stream>>>(queries, keys, frof,
                                       (const unsigned short*)zt, out);
}